// Round 2
// baseline (1338.629 us; speedup 1.0000x reference)
//
#include <hip/hip_runtime.h>
#include <hip/hip_bf16.h>

// GPR-GNN forward on MI355X. ALL float tensors are float32 (per harness contract:
// dtype follows the reference, which is f32 throughout). Output is float32.
// Pipeline per launch (d_ws re-poisoned every call, so everything is rebuilt):
//   1. edge_index storage probe (int32 vs int64) -- uniform branch, capture-safe
//   2. CSR-by-destination: count -> single-block scan -> scatter fill
//   3. 10x propagation: block per node, thread per feature, fused hidden accum
//   4. GEMM1 (hidden @ W1 + b1, relu), 64x64 tile, two K-stages, 33.8KB LDS
//   5. GEMM2 + log_softmax fused, one wave per node

#define NFEAT 128
#define HID   256
#define NCLS  40
#define KHOPS 10

// ---- storage probe: int64 values < 2^31 have all-zero odd 32-bit words ----
__global__ void k_detect64(const unsigned int* __restrict__ raw, int* __restrict__ flag) {
  __shared__ int any;
  int t = threadIdx.x;
  if (t == 0) any = 0;
  __syncthreads();
  if (raw[2 * t + 1] != 0u) any = 1;   // benign race: all writers store 1
  __syncthreads();
  if (t == 0) flag[0] = (any == 0) ? 1 : 0;   // 1 => int64 storage
}

__global__ void k_zero(int* __restrict__ p, int n) {
  int i = blockIdx.x * blockDim.x + threadIdx.x;
  if (i < n) p[i] = 0;
}

__global__ void k_count(const int* __restrict__ ei32, const long long* __restrict__ ei64,
                        int E, int N, int* __restrict__ cnt, const int* __restrict__ flag) {
  int e = blockIdx.x * blockDim.x + threadIdx.x;
  if (e >= E) return;
  int dst = flag[0] ? (int)ei64[(size_t)E + e] : ei32[(size_t)E + e];
  if ((unsigned)dst < (unsigned)N) atomicAdd(&cnt[dst], 1);
}

// single 1024-thread block: exclusive scan of cnt -> row_start[0..N], cursor copy,
// dinv = rsqrt(cnt+1) (self-loop makes deg >= 1 always).
__global__ void k_scan(const int* __restrict__ cnt, int* __restrict__ row_start,
                       int* __restrict__ cursor, float* __restrict__ dinv, int N) {
  __shared__ int wsum[16];
  __shared__ int carry;
  int tid = threadIdx.x;
  int lane = tid & 63, wid = tid >> 6;
  if (tid == 0) carry = 0;
  __syncthreads();
  for (int base = 0; base < N; base += 1024) {
    int idx = base + tid;
    int v = (idx < N) ? cnt[idx] : 0;
    int x = v;
    #pragma unroll
    for (int off = 1; off < 64; off <<= 1) {
      int t = __shfl_up(x, off);
      if (lane >= off) x += t;
    }
    if (lane == 63) wsum[wid] = x;
    __syncthreads();
    if (wid == 0) {
      int s = (lane < 16) ? wsum[lane] : 0;
      #pragma unroll
      for (int off = 1; off < 16; off <<= 1) {
        int t = __shfl_up(s, off);
        if (lane >= off) s += t;
      }
      if (lane < 16) wsum[lane] = s;
    }
    __syncthreads();
    int woff = wid ? wsum[wid - 1] : 0;
    int excl = x - v + woff;
    int c = carry;
    if (idx < N) {
      int rs = c + excl;
      row_start[idx] = rs;
      cursor[idx] = rs;
      dinv[idx] = rsqrtf((float)(v + 1));
    }
    __syncthreads();
    if (tid == 0) carry = c + wsum[15];
    __syncthreads();
  }
  if (tid == 0) row_start[N] = carry;
}

__global__ void k_fill(const int* __restrict__ ei32, const long long* __restrict__ ei64,
                       int E, int N, const float* __restrict__ dinv,
                       int* __restrict__ cursor, int* __restrict__ csr_src,
                       float* __restrict__ csr_w, const int* __restrict__ flag) {
  int e = blockIdx.x * blockDim.x + threadIdx.x;
  if (e >= E) return;
  int src, dst;
  if (flag[0]) { src = (int)ei64[e]; dst = (int)ei64[(size_t)E + e]; }
  else         { src = ei32[e];      dst = ei32[(size_t)E + e]; }
  if ((unsigned)src >= (unsigned)N || (unsigned)dst >= (unsigned)N) return;
  int p = atomicAdd(&cursor[dst], 1);
  csr_src[p] = src;
  csr_w[p] = dinv[src] * dinv[dst];
}

__global__ void k_init_h(const float* __restrict__ x, const float* __restrict__ temp,
                         float* __restrict__ h, float* __restrict__ hidden, int total) {
  int i = blockIdx.x * blockDim.x + threadIdx.x;
  if (i >= total) return;
  float v = x[i];
  h[i] = v;
  hidden[i] = temp[0] * v;
}

// one block per node, 128 threads = feature dim. Gathers are coalesced 512B rows.
__global__ __launch_bounds__(128) void k_prop(
    const float* __restrict__ h, float* __restrict__ h_new, float* __restrict__ hidden,
    const int* __restrict__ row_start, const int* __restrict__ csr_src,
    const float* __restrict__ csr_w, const float* __restrict__ dinv,
    const float* __restrict__ temp, int k) {
  int i = blockIdx.x;
  int f = threadIdx.x;
  float di = dinv[i];
  size_t base = (size_t)i * NFEAT + f;
  float acc = di * di * h[base];          // self-loop term: norm = dinv[i]^2
  int s = row_start[i], e = row_start[i + 1];
  for (int p = s; p < e; ++p) {
    int src = csr_src[p];
    float w = csr_w[p];
    acc += w * h[(size_t)src * NFEAT + f];
  }
  h_new[base] = acc;
  hidden[base] += temp[k + 1] * acc;      // thread owns (i,f): no atomic
}

// hidden (Mx128) @ W1 (128x256) + b1, relu -> Z (Mx256). 64x64 tile, K in two
// 64-stages. LDS stride 66: conflict-free B access, 2-way (free) A access.
__global__ __launch_bounds__(256) void k_gemm1(
    const float* __restrict__ A, const float* __restrict__ W1,
    const float* __restrict__ b1, float* __restrict__ Z, int M) {
  __shared__ float As[64][66];   // K-major: As[k][m]
  __shared__ float Bs[64][66];   // K-major: Bs[k][n]
  int tid = threadIdx.x;
  int m0 = blockIdx.x * 64, n0 = blockIdx.y * 64;
  int tm = (tid >> 4) << 2;
  int tn = (tid & 15) << 2;
  float acc[4][4] = {};
  for (int kk = 0; kk < NFEAT; kk += 64) {
    for (int idx = tid; idx < 64 * 64; idx += 256) {
      int m = idx >> 6, ka = idx & 63;     // consecutive tid -> consecutive k: coalesced
      int gr = m0 + m;
      As[ka][m] = (gr < M) ? A[(size_t)gr * NFEAT + kk + ka] : 0.f;
      int kb = idx >> 6, n = idx & 63;     // consecutive tid -> consecutive n: coalesced
      Bs[kb][n] = W1[(size_t)(kk + kb) * HID + n0 + n];
    }
    __syncthreads();
    #pragma unroll 8
    for (int k = 0; k < 64; ++k) {
      float2 a0 = *(const float2*)&As[k][tm];
      float2 a1 = *(const float2*)&As[k][tm + 2];
      float2 bx = *(const float2*)&Bs[k][tn];
      float2 by = *(const float2*)&Bs[k][tn + 2];
      float a4[4] = {a0.x, a0.y, a1.x, a1.y};
      float b4[4] = {bx.x, bx.y, by.x, by.y};
      #pragma unroll
      for (int i = 0; i < 4; ++i)
        #pragma unroll
        for (int j = 0; j < 4; ++j)
          acc[i][j] += a4[i] * b4[j];
    }
    __syncthreads();
  }
  float bias[4];
  #pragma unroll
  for (int j = 0; j < 4; ++j) bias[j] = b1[n0 + tn + j];
  #pragma unroll
  for (int i = 0; i < 4; ++i) {
    int row = m0 + tm + i;
    if (row < M) {
      float4 o;
      o.x = fmaxf(acc[i][0] + bias[0], 0.f);
      o.y = fmaxf(acc[i][1] + bias[1], 0.f);
      o.z = fmaxf(acc[i][2] + bias[2], 0.f);
      o.w = fmaxf(acc[i][3] + bias[3], 0.f);
      *(float4*)&Z[(size_t)row * HID + n0 + tn] = o;
    }
  }
}

// Z (Mx256) @ W2 (256x40) + b2 -> log_softmax -> out (f32). One wave per node.
__global__ __launch_bounds__(256) void k_mlp2(
    const float* __restrict__ z1, const float* __restrict__ W2,
    const float* __restrict__ b2, float* __restrict__ out, int N) {
  __shared__ __align__(16) float zrow[4][HID];
  int lane = threadIdx.x & 63;
  int wid = threadIdx.x >> 6;
  int node = blockIdx.x * 4 + wid;
  bool valid = node < N;
  float4 v = make_float4(0.f, 0.f, 0.f, 0.f);
  if (valid) v = *(const float4*)&z1[(size_t)node * HID + lane * 4];
  *(float4*)&zrow[wid][lane * 4] = v;
  __syncthreads();
  bool act = lane < NCLS;
  float acc = act ? b2[lane] : 0.f;
  const float* zr = zrow[wid];
  #pragma unroll 8
  for (int k = 0; k < HID; ++k) {
    float wv = act ? W2[k * NCLS + lane] : 0.f;   // W2 = 40KB, L1/L2-resident
    acc += zr[k] * wv;
  }
  float m = act ? acc : -3.4e38f;
  #pragma unroll
  for (int off = 32; off > 0; off >>= 1) m = fmaxf(m, __shfl_xor(m, off));
  float ex = act ? expf(acc - m) : 0.f;
  float ssum = ex;
  #pragma unroll
  for (int off = 32; off > 0; off >>= 1) ssum += __shfl_xor(ssum, off);
  float res = acc - m - logf(ssum);
  if (valid && act) out[(size_t)node * NCLS + lane] = res;
}

extern "C" void kernel_launch(void* const* d_in, const int* in_sizes, int n_in,
                              void* d_out, int out_size, void* d_ws, size_t ws_size,
                              hipStream_t stream) {
  const float*     x    = (const float*)d_in[0];
  const int*       ei32 = (const int*)d_in[1];
  const long long* ei64 = (const long long*)d_in[1];
  const float*     temp = (const float*)d_in[2];
  const float*     W1   = (const float*)d_in[3];
  const float*     b1   = (const float*)d_in[4];
  const float*     W2   = (const float*)d_in[5];
  const float*     b2   = (const float*)d_in[6];
  float* out = (float*)d_out;

  int N = in_sizes[0] / NFEAT;   // 50000
  int E = in_sizes[1] / 2;       // 800000

  // workspace carve (~84 MB; z1 aliases the dead h ping-pong after propagation)
  char* w = (char*)d_ws;
  auto carve = [&](size_t bytes) -> void* {
    void* p = (void*)w;
    w += (bytes + 255) & ~(size_t)255;
    return p;
  };
  int*   flag      = (int*)  carve(4);
  int*   cnt       = (int*)  carve((size_t)N * 4);
  int*   row_start = (int*)  carve(((size_t)N + 1) * 4);
  int*   cursor    = (int*)  carve((size_t)N * 4);
  float* dinv      = (float*)carve((size_t)N * 4);
  int*   csr_src   = (int*)  carve((size_t)E * 4);
  float* csr_w     = (float*)carve((size_t)E * 4);
  float* h_a       = (float*)carve((size_t)N * NFEAT * 4);
  float* h_b       = (float*)carve((size_t)N * NFEAT * 4);   // contiguous with h_a
  float* hidden    = (float*)carve((size_t)N * NFEAT * 4);
  float* z1        = h_a;   // 51.2MB = h_a+h_b region, dead once props finish

  k_detect64<<<1, 256, 0, stream>>>((const unsigned int*)d_in[1], flag);
  k_zero<<<(N + 255) / 256, 256, 0, stream>>>(cnt, N);
  k_count<<<(E + 255) / 256, 256, 0, stream>>>(ei32, ei64, E, N, cnt, flag);
  k_scan<<<1, 1024, 0, stream>>>(cnt, row_start, cursor, dinv, N);
  k_fill<<<(E + 255) / 256, 256, 0, stream>>>(ei32, ei64, E, N, dinv, cursor,
                                              csr_src, csr_w, flag);
  k_init_h<<<(N * NFEAT + 255) / 256, 256, 0, stream>>>(x, temp, h_a, hidden, N * NFEAT);

  float* hc = h_a;
  float* hn = h_b;
  for (int k = 0; k < KHOPS; ++k) {   // K fixed at 10 by the problem spec
    k_prop<<<N, NFEAT, 0, stream>>>(hc, hn, hidden, row_start, csr_src, csr_w,
                                    dinv, temp, k);
    float* t2 = hc; hc = hn; hn = t2;
  }

  k_gemm1<<<dim3((N + 63) / 64, HID / 64), 256, 0, stream>>>(hidden, W1, b1, z1, N);
  k_mlp2<<<(N + 3) / 4, 256, 0, stream>>>(z1, W2, b2, out, N);
}